// Round 5
// baseline (111.808 us; speedup 1.0000x reference)
//
#include <hip/hip_runtime.h>
#include <math.h>

typedef __attribute__((ext_vector_type(8))) short bf16x8;
typedef __attribute__((ext_vector_type(4))) float f32x4;
typedef __attribute__((ext_vector_type(4))) unsigned int u32x4;
typedef __attribute__((ext_vector_type(2))) unsigned int u32x2;

namespace {
constexpr int OUT0 = 2 * 32 * 16384;  // offset of att_mp inside d_out
}

// f32 -> bf16 RNE (pre-shift: result in high 16 bits)
__device__ __forceinline__ unsigned int bf16_rne(float f) {
  unsigned int u = __builtin_bit_cast(unsigned int, f);
  return u + 0x7fffu + ((u >> 16) & 1u);
}
// f32 -> bf16 round-half-up (1 VALU; tie-bias only, error ~= RNE)
__device__ __forceinline__ unsigned int bf16_rhu(float f) {
  return __builtin_bit_cast(unsigned int, f) + 0x8000u;
}
__device__ __forceinline__ unsigned int pack_rne(float lo, float hi) {
  return __builtin_amdgcn_perm(bf16_rne(hi), bf16_rne(lo), 0x07060302u);
}
__device__ __forceinline__ unsigned int pack_rhu(float lo, float hi) {
  return __builtin_amdgcn_perm(bf16_rhu(hi), bf16_rhu(lo), 0x07060302u);
}

// Prep: (a) pack w3 into per-lane bf16 B-fragments for mfma_f32_16x16x32_bf16:
//   dword f = ij*512 + nt*256 + lane*4 + d holds B[k0][o],B[k0+1][o],
//   k(=c) = (lane>>4)*8 + 2d, o = nt*16 + (lane&15).
// (b) wk[c*9+dd] = sum_o w2[o]*w1[o,c,dd]; wk[288] = w2.b1 + b2.
__global__ __launch_bounds__(256) void prep_kernel(
    const float* __restrict__ w1, const float* __restrict__ b1,
    const float* __restrict__ w2, const float* __restrict__ b2,
    const float* __restrict__ w3,
    float* __restrict__ wk, unsigned int* __restrict__ w3f) {
  int t = threadIdx.x, blk = blockIdx.x;
  if (blk < 98) {
    int f = blk * 256 + t;          // dword index, f < 25088
    int d = f & 3;
    int lane = (f >> 2) & 63;
    int nt = (f >> 8) & 1;
    int ij = f >> 9;                // 0..48
    int o = nt * 16 + (lane & 15);
    int k0 = ((lane >> 4) << 3) + 2 * d;
    float f0 = w3[o * 1568 + k0 * 49 + ij];
    float f1 = w3[o * 1568 + (k0 + 1) * 49 + ij];
    w3f[f] = pack_rne(f0, f1);
  } else {
    int k = (blk - 98) * 256 + t;
    if (k < 288) {
      int c = k / 9, r = k - c * 9;
      float s = 0.f;
#pragma unroll
      for (int o = 0; o < 32; ++o) s += w2[o] * w1[o * 288 + c * 9 + r];
      wk[k] = s;
    } else if (k == 288) {
      float s = b2[0];
#pragma unroll
      for (int o = 0; o < 32; ++o) s += w2[o] * b1[o];
      wk[288] = s;
    }
  }
}

// Fused kernel: one 8x8 pixel tile per block (512 blocks, 256 threads).
__global__ __launch_bounds__(256) void fused_kernel(
    const float* __restrict__ x, const float* __restrict__ wk,
    const unsigned int* __restrict__ w3f, const float* __restrict__ b3,
    float* __restrict__ out, float* __restrict__ att_out) {
  // regionA: xs f32 tile (phases 1-1b), then aliased as as_ = g-tile (2+).
  __shared__ float regionA[9216];          // 36,864 B
  __shared__ float ys[9 * 224];            //  8,064 B  y[dd][(r-1)*16+cc], rows 1..14
  __shared__ unsigned short xh[224 * 40];  // 17,920 B  bf16 x, rows 1..14, stride 40
  __shared__ float wks[289];               //  1,156 B   (total 64,004 B)
  float* xs = regionA;                     // xs[sp*36 + c]
  float* as_ = regionA;                    // as_[pos*68 + px] = 1 + att

  int t = threadIdx.x;
  int bi = blockIdx.x;
  int b = bi >> 8;
  int tile = bi & 255;
  int y0 = (tile >> 4) << 3, x0 = (tile & 15) << 3;
  const float* xb = x + ((long)b << 19);

  for (int k = t; k < 289; k += 256) wks[k] = wk[k];

  // ---- phase 1: stage x tile + halo(4) via float4 (segments fully in/out) ----
#pragma unroll
  for (int it = 0; it < 8; ++it) {
    int idx = it * 256 + t;
    int c = idx >> 6;
    int r64 = idx & 63;
    int row = r64 >> 2, seg = r64 & 3;
    int gy = y0 + row - 4;
    int gxs = x0 + (seg << 2) - 4;
    f32x4 v = {0.f, 0.f, 0.f, 0.f};
    if ((unsigned)gy < 128u && (unsigned)gxs < 128u)
      v = *reinterpret_cast<const f32x4*>(xb + (c << 14) + (gy << 7) + gxs);
    int sp = (row << 4) + (seg << 2);
#pragma unroll
    for (int e = 0; e < 4; ++e) xs[(sp + e) * 36 + c] = v[e];
  }
  __syncthreads();

  // ---- phase 1b: y[dd] = sum_c x*wk  AND bf16-pack x into xh (once) ----
  {
    int r = t >> 4, cc = t & 15;
    bool inner = (unsigned)(r - 1) < 14u;     // rows 1..14 only are ever read
    int n = (r - 1) * 16 + cc;                // xh/ys row-rebased index
    float s[9];
#pragma unroll
    for (int dd = 0; dd < 9; ++dd) s[dd] = 0.f;
#pragma unroll
    for (int c4 = 0; c4 < 8; ++c4) {
      f32x4 xv = *reinterpret_cast<const f32x4*>(&xs[t * 36 + c4 * 4]);
#pragma unroll
      for (int e = 0; e < 4; ++e) {
        int c = c4 * 4 + e;
#pragma unroll
        for (int dd = 0; dd < 9; ++dd) s[dd] += xv[e] * wks[c * 9 + dd];
      }
      if (inner) {
        u32x2 p;
        p[0] = pack_rhu(xv[0], xv[1]);
        p[1] = pack_rhu(xv[2], xv[3]);
        *reinterpret_cast<u32x2*>(&xh[n * 40 + c4 * 4]) = p;  // 8B aligned
      }
    }
    if (inner) {
#pragma unroll
      for (int dd = 0; dd < 9; ++dd) ys[dd * 224 + n] = s[dd];
    }
  }
  __syncthreads();

  // ---- phase 2: as_[pos][px] = 1 + sigmoid(bk + sum_{valid taps} y) ----
  {
    int px = t & 63, wv = t >> 6;
    int py = px >> 3, pxl = px & 7;
#pragma unroll 1
    for (int it = 0; it < 13; ++it) {
      int pos = wv * 13 + it;
      if (pos < 49) {
        int i = pos / 7, j = pos - i * 7;
        float s = wks[288];
#pragma unroll
        for (int di = 0; di < 3; ++di) {
          int ii = i + di - 1;
          if ((unsigned)ii >= 7u) continue;
#pragma unroll
          for (int dj = 0; dj < 3; ++dj) {
            int jj = j + dj - 1;
            if ((unsigned)jj >= 7u) continue;
            s += ys[(di * 3 + dj) * 224 + (py + ii) * 16 + (pxl + jj + 1)];
          }
        }
        as_[pos * 68 + px] = 1.f + 1.f / (1.f + expf(-s));
      }
    }
  }
  __syncthreads();

  // ---- phase 2.5: coalesced att_out stores (att = g - 1) ----
  {
#pragma unroll 1
    for (int it = 0; it < 13; ++it) {
      int f = it * 256 + t;
      if (f < 3136) {
        int row = f / 392;
        int rem = f - row * 392;
        int pxl = rem / 49;
        int pos = rem - pxl * 49;
        long base = ((long)(b << 14) + ((y0 + row) << 7) + x0) * 49;
        att_out[base + rem] = as_[pos * 68 + (row << 3) + pxl] - 1.f;
      }
    }
  }

  // ---- phase 3: per tap P = A(bf16 x)*B, then acc += g[row]*P (gate in f32) ----
  int lane = t & 63, wv = t >> 6;
  int ml = lane & 15, q = lane >> 4;
  int px = wv * 16 + ml;
  int py = px >> 3, pxl = px & 7;
  int grow = wv * 16 + (q << 2);           // D rows q*4+r, contiguous in as_
  f32x4 acc0 = {0.f, 0.f, 0.f, 0.f}, acc1 = {0.f, 0.f, 0.f, 0.f};
  const u32x4* bp = reinterpret_cast<const u32x4*>(w3f) + lane;
#pragma unroll 1
  for (int i = 0; i < 7; ++i) {
    int nb = (py + i) * 16 + pxl + 1;      // xh row index for j=0
#pragma unroll
    for (int j = 0; j < 7; ++j) {
      int ij = i * 7 + j;
      u32x4 bw0 = bp[(ij * 2 + 0) * 64];
      u32x4 bw1 = bp[(ij * 2 + 1) * 64];
      bf16x8 af = *reinterpret_cast<const bf16x8*>(&xh[(nb + j) * 40 + (q << 3)]);
      f32x4 gv = *reinterpret_cast<const f32x4*>(&as_[ij * 68 + grow]);
      f32x4 z = {0.f, 0.f, 0.f, 0.f};
      f32x4 P0 = __builtin_amdgcn_mfma_f32_16x16x32_bf16(
          af, __builtin_bit_cast(bf16x8, bw0), z, 0, 0, 0);
      f32x4 P1 = __builtin_amdgcn_mfma_f32_16x16x32_bf16(
          af, __builtin_bit_cast(bf16x8, bw1), z, 0, 0, 0);
#pragma unroll
      for (int r = 0; r < 4; ++r) {
        acc0[r] += gv[r] * P0[r];
        acc1[r] += gv[r] * P1[r];
      }
    }
  }
  __syncthreads();   // as_ g-reads done; reuse as_ for output transpose

  // ---- epilogue: D col=lane&15(=o), row=q*4+reg(=px) -> LDS [o][px] ----
  {
    float bv0 = b3[ml], bv1 = b3[16 + ml];
#pragma unroll
    for (int r = 0; r < 4; ++r) {
      int pxd = (wv << 4) + (q << 2) + r;
      as_[ml * 68 + pxd] = acc0[r] + bv0;
      as_[(16 + ml) * 68 + pxd] = acc1[r] + bv1;
    }
  }
  __syncthreads();
#pragma unroll
  for (int rep = 0; rep < 8; ++rep) {
    int idx = rep * 256 + t;
    int o = idx >> 6, pxs = idx & 63;
    out[((long)b << 19) + (o << 14) + ((y0 + (pxs >> 3)) << 7) + x0 + (pxs & 7)]
        = as_[o * 68 + pxs];
  }
}

extern "C" void kernel_launch(void* const* d_in, const int* in_sizes, int n_in,
                              void* d_out, int out_size, void* d_ws, size_t ws_size,
                              hipStream_t stream) {
  const float* x  = (const float*)d_in[0];
  const float* w1 = (const float*)d_in[1];
  const float* b1 = (const float*)d_in[2];
  const float* w2 = (const float*)d_in[3];
  const float* b2 = (const float*)d_in[4];
  const float* w3 = (const float*)d_in[5];
  const float* b3 = (const float*)d_in[6];

  float* out = (float*)d_out;
  float* att_out = out + OUT0;
  float* wk = (float*)d_ws;                                // 289 floats
  unsigned int* w3f = (unsigned int*)((char*)d_ws + 4096); // 25088 dwords

  prep_kernel<<<100, 256, 0, stream>>>(w1, b1, w2, b2, w3, wk, w3f);
  fused_kernel<<<512, 256, 0, stream>>>(x, wk, w3f, b3, out, att_out);
}

// Round 6
// 89.934 us; speedup vs baseline: 1.2432x; 1.2432x over previous
//
#include <hip/hip_runtime.h>
#include <math.h>

typedef __attribute__((ext_vector_type(8))) short bf16x8;
typedef __attribute__((ext_vector_type(4))) float f32x4;
typedef __attribute__((ext_vector_type(4))) unsigned int u32x4;
typedef __attribute__((ext_vector_type(2))) unsigned int u32x2;

namespace {
constexpr int OUT0 = 2 * 32 * 16384;  // offset of att_mp inside d_out
}

// f32 -> bf16 RNE (pre-shift: result in high 16 bits)
__device__ __forceinline__ unsigned int bf16_rne(float f) {
  unsigned int u = __builtin_bit_cast(unsigned int, f);
  return u + 0x7fffu + ((u >> 16) & 1u);
}
// f32 -> bf16 round-half-up (1 VALU; tie-bias only)
__device__ __forceinline__ unsigned int bf16_rhu(float f) {
  return __builtin_bit_cast(unsigned int, f) + 0x8000u;
}
__device__ __forceinline__ unsigned int pack_rne(float lo, float hi) {
  return __builtin_amdgcn_perm(bf16_rne(hi), bf16_rne(lo), 0x07060302u);
}
__device__ __forceinline__ unsigned int pack_rhu(float lo, float hi) {
  return __builtin_amdgcn_perm(bf16_rhu(hi), bf16_rhu(lo), 0x07060302u);
}
__device__ __forceinline__ float bf16_to_f32(unsigned int u16v) {
  return __builtin_bit_cast(float, u16v << 16);
}

// Prep: (a) pack w3 into per-lane bf16 B-fragments for mfma_f32_16x16x32_bf16:
//   u32x4 index = ij*128 + oh*64 + lane; dword d: B[k0][o],B[k0+1][o],
//   k(=c) = (lane>>4)*8 + 2d, o = oh*16 + (lane&15).
// (b) wk[c*9+dd] = sum_o w2[o]*w1[o,c,dd]; wk[288] = w2.b1 + b2.
__global__ __launch_bounds__(256) void prep_kernel(
    const float* __restrict__ w1, const float* __restrict__ b1,
    const float* __restrict__ w2, const float* __restrict__ b2,
    const float* __restrict__ w3,
    float* __restrict__ wk, unsigned int* __restrict__ w3f) {
  int t = threadIdx.x, blk = blockIdx.x;
  if (blk < 98) {
    int f = blk * 256 + t;          // dword index, f < 25088
    int d = f & 3;
    int lane = (f >> 2) & 63;
    int nt = (f >> 8) & 1;
    int ij = f >> 9;                // 0..48
    int o = nt * 16 + (lane & 15);
    int k0 = ((lane >> 4) << 3) + 2 * d;
    float f0 = w3[o * 1568 + k0 * 49 + ij];
    float f1 = w3[o * 1568 + (k0 + 1) * 49 + ij];
    w3f[f] = pack_rne(f0, f1);
  } else {
    int k = (blk - 98) * 256 + t;
    if (k < 288) {
      int c = k / 9, r = k - c * 9;
      float s = 0.f;
#pragma unroll
      for (int o = 0; o < 32; ++o) s += w2[o] * w1[o * 288 + c * 9 + r];
      wk[k] = s;
    } else if (k == 288) {
      float s = b2[0];
#pragma unroll
      for (int o = 0; o < 32; ++o) s += w2[o] * b1[o];
      wk[288] = s;
    }
  }
}

// Fused kernel: one 8x8 pixel tile per block; 512 blocks x 512 threads (8 waves).
__global__ __launch_bounds__(512, 4) void fused_kernel(
    const float* __restrict__ x, const float* __restrict__ wk,
    const unsigned int* __restrict__ w3f, const float* __restrict__ b3,
    float* __restrict__ out, float* __restrict__ att_out) {
  // regA: phase1-1b = xs16 bf16 planar [c][sp] (8192 u16); phase2+ = as_ g-tile.
  __shared__ __align__(16) char regA[16384];
  unsigned short* xs16 = (unsigned short*)regA;   // xs16[c*256 + sp]
  float* as_ = (float*)regA;                      // as_[pos*68 + px] = 1+att
  __shared__ __align__(16) unsigned short xh[224 * 40];  // bf16 x [sp'][c], rows 1..14
  __shared__ unsigned short ysb[9 * 224];         // bf16 y[dd][(r-1)*16+cc]
  __shared__ float wks[289];

  int t = threadIdx.x;
  int bi = blockIdx.x;
  int b = bi >> 8;
  int tile = bi & 255;
  int y0 = (tile >> 4) << 3, x0 = (tile & 15) << 3;
  const float* xb = x + ((long)b << 19);

  for (int k = t; k < 289; k += 512) wks[k] = wk[k];

  // ---- phase 1: global f32x4 -> bf16 -> planar xs16 (conflict-free b64) ----
#pragma unroll
  for (int it = 0; it < 4; ++it) {
    int idx = it * 512 + t;
    int c = idx >> 6;                 // wave-uniform
    int r64 = idx & 63;               // 4-pixel segment id; sp = 4*r64
    int row = r64 >> 2, seg = r64 & 3;
    int gy = y0 + row - 4;
    int gxs = x0 + (seg << 2) - 4;
    f32x4 v = {0.f, 0.f, 0.f, 0.f};
    if ((unsigned)gy < 128u && (unsigned)gxs < 128u)
      v = *reinterpret_cast<const f32x4*>(xb + (c << 14) + (gy << 7) + gxs);
    u32x2 p;
    p[0] = pack_rhu(v[0], v[1]);
    p[1] = pack_rhu(v[2], v[3]);
    *reinterpret_cast<u32x2*>(reinterpret_cast<unsigned int*>(xs16) +
                              (c << 7) + (r64 << 1)) = p;
  }
  __syncthreads();

  // ---- phase 1b (t<256, thread=pixel): y[9] + transpose-pack xh ----
  if (t < 256) {
    int r = t >> 4;
    bool inner = (unsigned)(r - 1) < 14u;   // rows 1..14 are the used window
    int n = t - 16;                         // rebased row-major index
    unsigned int u[32];
#pragma unroll
    for (int c = 0; c < 32; ++c) u[c] = xs16[(c << 8) + t];
    float s[9];
#pragma unroll
    for (int dd = 0; dd < 9; ++dd) s[dd] = 0.f;
#pragma unroll
    for (int c = 0; c < 32; ++c) {
      float xf = bf16_to_f32(u[c]);
#pragma unroll
      for (int dd = 0; dd < 9; ++dd) s[dd] += xf * wks[c * 9 + dd];
    }
    if (inner) {
#pragma unroll
      for (int dd = 0; dd < 9; ++dd)
        ysb[dd * 224 + n] = (unsigned short)(bf16_rhu(s[dd]) >> 16);
      unsigned int* xhd = reinterpret_cast<unsigned int*>(xh) + n * 20;
#pragma unroll
      for (int g4 = 0; g4 < 4; ++g4) {
        u32x4 d;
#pragma unroll
        for (int e = 0; e < 4; ++e) {
          int k2 = g4 * 4 + e;
          d[e] = __builtin_amdgcn_perm(u[2 * k2 + 1], u[2 * k2], 0x05040100u);
        }
        *reinterpret_cast<u32x4*>(xhd + g4 * 4) = d;
      }
    }
  }
  __syncthreads();

  // ---- phase 2: as_[pos][px] = 1 + sigmoid(bk + sum_valid y) ----
#pragma unroll 1
  for (int it = 0; it < 7; ++it) {
    int f = it * 512 + t;
    if (f < 3136) {
      int pos = f >> 6;               // wave-uniform
      int px = f & 63;
      int py = px >> 3, pxl = px & 7;
      int i = pos / 7, j = pos - i * 7;
      float s = wks[288];
#pragma unroll
      for (int di = 0; di < 3; ++di) {
        int ii = i + di - 1;
        if ((unsigned)ii >= 7u) continue;
#pragma unroll
        for (int dj = 0; dj < 3; ++dj) {
          int jj = j + dj - 1;
          if ((unsigned)jj >= 7u) continue;
          s += bf16_to_f32(
              (unsigned int)ysb[(di * 3 + dj) * 224 + (py + ii) * 16 + pxl + jj + 1]);
        }
      }
      as_[pos * 68 + px] = 1.f + 1.f / (1.f + expf(-s));
    }
  }
  __syncthreads();

  // ---- phase 2.5: coalesced att_out stores (att = g - 1) ----
#pragma unroll 1
  for (int it = 0; it < 7; ++it) {
    int f = it * 512 + t;
    if (f < 3136) {
      int row = f / 392;
      int rem = f - row * 392;
      int pxl = rem / 49;
      int pos = rem - pxl * 49;
      long base = ((long)(b << 14) + ((y0 + row) << 7) + x0) * 49;
      att_out[base + rem] = as_[pos * 68 + (row << 3) + pxl] - 1.f;
    }
  }

  // ---- phase 3: wave w -> m-tile (w>>1), o-half (w&1); 1 MFMA per tap ----
  int wv = t >> 6, lane = t & 63;
  int mt = wv >> 1, oh = wv & 1;
  int ml = lane & 15, q = lane >> 4;
  int px = mt * 16 + ml;               // A-row pixel for this lane
  int py = px >> 3, pxl = px & 7;
  f32x4 acc = {0.f, 0.f, 0.f, 0.f};
  const u32x4* bp = reinterpret_cast<const u32x4*>(w3f) + lane + oh * 64;
#pragma unroll 1
  for (int i = 0; i < 7; ++i) {
    int nb = (py + i) * 16 + pxl + 1;
#pragma unroll
    for (int j = 0; j < 7; ++j) {
      int ij = i * 7 + j;
      u32x4 bw = bp[ij * 128];
      bf16x8 af = *reinterpret_cast<const bf16x8*>(&xh[(nb + j) * 40 + (q << 3)]);
      f32x4 gv = *reinterpret_cast<const f32x4*>(&as_[ij * 68 + mt * 16 + (q << 2)]);
      f32x4 z = {0.f, 0.f, 0.f, 0.f};
      f32x4 P = __builtin_amdgcn_mfma_f32_16x16x32_bf16(
          af, __builtin_bit_cast(bf16x8, bw), z, 0, 0, 0);
#pragma unroll
      for (int r = 0; r < 4; ++r) acc[r] += gv[r] * P[r];
    }
  }
  __syncthreads();   // g-reads done; reuse as_ for the output transpose

  // ---- epilogue: D col=lane&15 -> o = oh*16+ml, row=q*4+r -> px ----
  {
    int o = oh * 16 + ml;
    float bv = b3[o];
#pragma unroll
    for (int r = 0; r < 4; ++r)
      as_[o * 68 + mt * 16 + (q << 2) + r] = acc[r] + bv;
  }
  __syncthreads();
#pragma unroll
  for (int rep = 0; rep < 4; ++rep) {
    int idx = rep * 512 + t;
    int o = idx >> 6, pxs = idx & 63;
    out[((long)b << 19) + (o << 14) + ((y0 + (pxs >> 3)) << 7) + x0 + (pxs & 7)]
        = as_[o * 68 + pxs];
  }
}

extern "C" void kernel_launch(void* const* d_in, const int* in_sizes, int n_in,
                              void* d_out, int out_size, void* d_ws, size_t ws_size,
                              hipStream_t stream) {
  const float* x  = (const float*)d_in[0];
  const float* w1 = (const float*)d_in[1];
  const float* b1 = (const float*)d_in[2];
  const float* w2 = (const float*)d_in[3];
  const float* b2 = (const float*)d_in[4];
  const float* w3 = (const float*)d_in[5];
  const float* b3 = (const float*)d_in[6];

  float* out = (float*)d_out;
  float* att_out = out + OUT0;
  float* wk = (float*)d_ws;                                // 289 floats
  unsigned int* w3f = (unsigned int*)((char*)d_ws + 4096); // 25088 dwords

  prep_kernel<<<100, 256, 0, stream>>>(w1, b1, w2, b2, w3, wk, w3f);
  fused_kernel<<<512, 512, 0, stream>>>(x, wk, w3f, b3, out, att_out);
}